// Round 5
// baseline (577.113 us; speedup 1.0000x reference)
//
#include <hip/hip_runtime.h>

#define B_ 4
#define T_ 2048
#define C_ 2048
#define H_ 16
#define HD_ 128
#define BT_ (B_*T_)
#define N3_ (3*C_)

typedef unsigned short u16;
typedef unsigned int u32;
using short8 = __attribute__((ext_vector_type(8))) short;
using f32x4  = __attribute__((ext_vector_type(4))) float;

__device__ __forceinline__ u16 f2bf(float f) {
  union { float f; u32 u; } v; v.f = f;
  u32 r = v.u + 0x7FFFu + ((v.u >> 16) & 1u);
  return (u16)(r >> 16);
}
__device__ __forceinline__ float bf2f(u16 u) {
  union { u32 u; float f; } v; v.u = ((u32)u) << 16;
  return v.f;
}
__device__ __forceinline__ void gload_lds16(const void* g, void* l) {
  __builtin_amdgcn_global_load_lds((const __attribute__((address_space(1))) void*)g,
                                   (__attribute__((address_space(3))) void*)l, 16, 0, 0);
}

// ---------------- cast fp32 -> bf16 ----------------
__global__ __launch_bounds__(256) void cast_f2b_kernel(const float* __restrict__ in,
                                                       u16* __restrict__ out, int n4) {
  int i = blockIdx.x * 256 + threadIdx.x;
  if (i >= n4) return;
  float4 v = ((const float4*)in)[i];
  ushort4 o;
  o.x = f2bf(v.x); o.y = f2bf(v.y); o.z = f2bf(v.z); o.w = f2bf(v.w);
  ((ushort4*)out)[i] = o;
}

// ---------------- RoPE cos/sin table [T][64] ----------------
__global__ __launch_bounds__(256) void rope_table_kernel(float* __restrict__ cosb,
                                                         float* __restrict__ sinb) {
  int i = blockIdx.x * 256 + threadIdx.x;
  int t = i >> 6, d = i & 63;
  float inv = powf(10000.0f, -(float)d / 64.0f);
  float ang = (float)t * inv;
  cosb[i] = cosf(ang);
  sinb[i] = sinf(ang);
}

// ---------------- RoPE apply + split qkv ----------------
__global__ __launch_bounds__(256) void rope_apply_kernel(const u16* __restrict__ qkv,
    const float* __restrict__ cosb, const float* __restrict__ sinb,
    u16* __restrict__ qb, u16* __restrict__ kbb,
    float* __restrict__ kout, float* __restrict__ vout) {
  int gid = blockIdx.x * 256 + threadIdx.x;   // B*T*H*64 threads
  int d = gid & 63;
  int h = (gid >> 6) & 15;
  int t = (gid >> 10) & 2047;
  int b = gid >> 21;
  const u16* row = qkv + (size_t)(b * T_ + t) * N3_;
  int base = h * HD_ + d;
  const float SCALE = 0.08838834764831845f; // 1/sqrt(128), folded into Q
  float q0 = bf2f(row[base]);
  float q1 = bf2f(row[base + 64]);
  float k0 = bf2f(row[C_ + base]);
  float k1 = bf2f(row[C_ + base + 64]);
  float v0 = bf2f(row[2*C_ + base]);
  float v1 = bf2f(row[2*C_ + base + 64]);
  float c = cosb[t * 64 + d], s = sinb[t * 64 + d];
  size_t o = ((size_t)((b * H_ + h) * T_ + t)) * HD_ + d;
  qb[o]        = f2bf((q0 * c - q1 * s) * SCALE);
  qb[o + 64]   = f2bf((q1 * c + q0 * s) * SCALE);
  float kr0 = k0 * c - k1 * s;
  float kr1 = k1 * c + k0 * s;
  kout[o]      = kr0;
  kout[o + 64] = kr1;
  kbb[o]       = f2bf(kr0);
  kbb[o + 64]  = f2bf(kr1);
  vout[o]      = v0;
  vout[o + 64] = v1;
}

// ---------------- V transpose: qkv bf16 -> Vt bf16 [B,H,hd,T] ----------------
__global__ __launch_bounds__(256) void vt_kernel(const u16* __restrict__ qkvb,
                                                 u16* __restrict__ vtb) {
  __shared__ u16 tile[64][72];
  int bid = blockIdx.x;          // bh(64) * ttile(32) * dhalf(2)
  int dh = bid & 1, tt = (bid >> 1) & 31, bh = bid >> 6;
  int b = bh >> 4, h = bh & 15;
  int tid = threadIdx.x;
  int tr = tid >> 2, tc = tid & 3;
  const u16* src = qkvb + (size_t)(b*T_ + tt*64 + tr) * N3_ + 2*C_ + h*HD_ + dh*64 + tc*16;
  short8 v0 = *(const short8*)src;
  short8 v1 = *(const short8*)(src + 8);
  #pragma unroll
  for (int j = 0; j < 8; ++j) {
    tile[tr][tc*16 + j]     = (u16)v0[j];
    tile[tr][tc*16 + 8 + j] = (u16)v1[j];
  }
  __syncthreads();
  int dr = tid >> 2, c2 = tid & 3;
  short8 o0, o1;
  #pragma unroll
  for (int j = 0; j < 8; ++j) {
    o0[j] = (short)tile[c2*16 + j][dr];
    o1[j] = (short)tile[c2*16 + 8 + j][dr];
  }
  u16* dst = vtb + ((size_t)bh * HD_ + dh*64 + dr) * T_ + tt*64 + c2*16;
  *(short8*)dst = o0;
  *(short8*)(dst + 8) = o1;
}

// ---------------- bf16 GEMM, C = A @ B^T : 256x256, 8-wave, 4-ring, reg-pipelined ----------------
// T2: permuted-chunk LDS (0 bank conflicts measured R4).
// T3+T4: ring-4 LDS, counted vmcnt(4) per tile (never drains mid-pipeline).
// NEW (R5): register fragment double-buffer -- phase-p MFMAs use operands read
// in phase p-1, so the LDS pipe drains under the MFMA issue window.
// Residency proof: at end of tile t-1, vmcnt(4) leaves only t+2's 4 loads in
// flight => tiles <= t+1 landed => phase-B reads of tile t+1 during tile t are safe.
// Ring slots during tile t: read {t,t+1}, landing {t+2}, staging {t+3} -- all distinct mod 4.
template<int OUT_BF16>
__global__ __launch_bounds__(512, 2) void gemm8p_kernel(const u16* __restrict__ A,
    const u16* __restrict__ Bw, void* __restrict__ Cout, int M, int N, int K, int ntx) {
  extern __shared__ u16 ldsx[];   // 4 bufs x (A 8192 u16 + B 8192 u16) = 128 KiB
  int lin = blockIdx.x;
  int cpx = gridDim.x >> 3;                      // grid % 8 == 0
  int wg = (lin & 7) * cpx + (lin >> 3);
  int mtile = wg / ntx, ntile = wg - mtile * ntx;
  int tid = threadIdx.x, w = tid >> 6, l = tid & 63;
  int lr = l & 15, lg = l >> 4;
  int wr = w >> 2, wc = w & 3;                   // 2x4 wave grid
  const u16* Abase = A + (size_t)mtile * 256 * K;
  const u16* Bbase = Bw + (size_t)ntile * 256 * K;

  // staging: LDS chunk s=(j*8+w)*64+l; global row=(s>>5)*8+(s&7), kchunk=(s&31)>>3
  int goff[2], ldsoff[2];
  #pragma unroll
  for (int j = 0; j < 2; ++j) {
    int s = (j*8 + w)*64 + l;
    int row = (s >> 5)*8 + (s & 7);
    int c = (s & 31) >> 3;
    goff[j] = row * K + c*8;
    ldsoff[j] = (j*8 + w) * 512;
  }
  // read-side byte offsets: byte(row,lg) = (row&~7)*64 + lg*128 + (row&7)*16
  int bbyte[4], abyte[2][4];
  #pragma unroll
  for (int n = 0; n < 4; ++n) {
    int r = wc*64 + n*16 + lr;
    bbyte[n] = ((r & ~7) << 6) + (lg << 7) + ((r & 7) << 4);
  }
  #pragma unroll
  for (int mq = 0; mq < 2; ++mq)
    #pragma unroll
    for (int m = 0; m < 4; ++m) {
      int r = wr*128 + mq*64 + m*16 + lr;
      abyte[mq][m] = ((r & ~7) << 6) + (lg << 7) + ((r & 7) << 4);
    }

  f32x4 acc[8][4];
  #pragma unroll
  for (int mi = 0; mi < 8; ++mi)
    #pragma unroll
    for (int n = 0; n < 4; ++n) acc[mi][n] = (f32x4){0.f,0.f,0.f,0.f};

  const int NT = K >> 5;
  // prologue: stage tiles 0,1,2 (12 loads/thread); vmcnt(4) => tiles 0,1 landed
  #pragma unroll
  for (int t0 = 0; t0 < 3; ++t0) {
    const u16* ga = Abase + t0*32;
    const u16* gb = Bbase + t0*32;
    u16* la = ldsx + (size_t)t0 * 16384;
    #pragma unroll
    for (int j = 0; j < 2; ++j) gload_lds16(ga + goff[j], la + ldsoff[j]);
    #pragma unroll
    for (int j = 0; j < 2; ++j) gload_lds16(gb + goff[j], la + 8192 + ldsoff[j]);
  }
  asm volatile("s_waitcnt vmcnt(4)" ::: "memory");
  __builtin_amdgcn_s_barrier();

  // preload tile-0 fragments
  short8 bf[4], af0[4];
  {
    const char* Al0 = (const char*)ldsx;
    #pragma unroll
    for (int n = 0; n < 4; ++n) bf[n] = *(const short8*)(Al0 + 16384 + bbyte[n]);
    #pragma unroll
    for (int m = 0; m < 4; ++m) af0[m] = *(const short8*)(Al0 + abyte[0][m]);
  }

  #pragma unroll 2
  for (int t = 0; t < NT; ++t) {
    const char* Al  = (const char*)(ldsx + (size_t)(t & 3) * 16384);
    const char* Aln = (const char*)(ldsx + (size_t)((t+1) & 3) * 16384);
    int tp = t + 3;
    bool st = tp < NT;
    u16* lp = ldsx + (size_t)(tp & 3) * 16384;
    short8 af1[4], bfn[4], afn[4];
    // ---- phase A: stage A(t+3); read af1 (tile t, mq=1); MFMA mq=0 (preloaded operands)
    if (st) {
      const u16* ga = Abase + tp*32;
      #pragma unroll
      for (int j = 0; j < 2; ++j) gload_lds16(ga + goff[j], lp + ldsoff[j]);
    }
    #pragma unroll
    for (int m = 0; m < 4; ++m) af1[m] = *(const short8*)(Al + abyte[1][m]);
    __builtin_amdgcn_s_setprio(1);
    #pragma unroll
    for (int m = 0; m < 4; ++m)
      #pragma unroll
      for (int n = 0; n < 4; ++n)
        acc[m][n] = __builtin_amdgcn_mfma_f32_16x16x32_bf16(af0[m], bf[n], acc[m][n], 0, 0, 0);
    __builtin_amdgcn_s_setprio(0);
    // ---- phase B: stage B(t+3); read tile t+1 frags; MFMA mq=1 (af1)
    if (st) {
      const u16* gb = Bbase + tp*32;
      #pragma unroll
      for (int j = 0; j < 2; ++j) gload_lds16(gb + goff[j], lp + 8192 + ldsoff[j]);
    }
    if (t + 1 < NT) {
      #pragma unroll
      for (int n = 0; n < 4; ++n) bfn[n] = *(const short8*)(Aln + 16384 + bbyte[n]);
      #pragma unroll
      for (int m = 0; m < 4; ++m) afn[m] = *(const short8*)(Aln + abyte[0][m]);
    }
    __builtin_amdgcn_s_setprio(1);
    #pragma unroll
    for (int m = 0; m < 4; ++m)
      #pragma unroll
      for (int n = 0; n < 4; ++n)
        acc[4+m][n] = __builtin_amdgcn_mfma_f32_16x16x32_bf16(af1[m], bf[n], acc[4+m][n], 0, 0, 0);
    __builtin_amdgcn_s_setprio(0);
    // counted wait: guarantee tile t+1 landed for next iteration's reads
    if (t >= NT - 3) { asm volatile("s_waitcnt vmcnt(0)" ::: "memory"); }
    else             { asm volatile("s_waitcnt vmcnt(4)" ::: "memory"); }
    __builtin_amdgcn_s_barrier();
    if (t + 1 < NT) {
      #pragma unroll
      for (int n = 0; n < 4; ++n) bf[n] = bfn[n];
      #pragma unroll
      for (int m = 0; m < 4; ++m) af0[m] = afn[m];
    }
  }
  // epilogue
  #pragma unroll
  for (int mi = 0; mi < 8; ++mi)
    #pragma unroll
    for (int n = 0; n < 4; ++n)
      #pragma unroll
      for (int r = 0; r < 4; ++r) {
        int grow = mtile*256 + wr*128 + mi*16 + lg*4 + r;
        int gcol = ntile*256 + wc*64 + n*16 + lr;
        float v = acc[mi][n][r];
        if (OUT_BF16) ((u16*)Cout)[(size_t)grow * N + gcol] = f2bf(v);
        else          ((float*)Cout)[(size_t)grow * N + gcol] = v;
      }
}

// ---------------- causal flash attention, paired q-tiles, dbuf gload_lds ----------------
struct TileSt {
  short8 aq[4];
  f32x4 oacc[8];
  float m_run[4];
  float l_run[4];
};

__device__ __forceinline__ void stage_kv(const u16* kpl, const u16* vpl, int kt,
                                         u16* Kd, u16* Vd, int w, int l) {
  const u16* kTile = kpl + (size_t)kt * 64 * HD_;
  int ktOff = kt * 64;
  #pragma unroll
  for (int j = 0; j < 4; ++j) {
    int s = (j*4 + w)*64 + l;
    int g = s ^ ((s >> 4) & 7);            // K: 16 chunks/row, XOR (row&7)
    gload_lds16(kTile + (g >> 4)*HD_ + (g & 15)*8, (char*)Kd + (j*4 + w)*1024);
    int g2 = s ^ ((s >> 3) & 7);           // Vt: 8 chunks/row, XOR (d&7)
    gload_lds16(vpl + (size_t)(g2 >> 3)*T_ + ktOff + (g2 & 7)*8, (char*)Vd + (j*4 + w)*1024);
  }
}

__device__ __forceinline__ void attn_tile(TileSt& st, const u16* Kl, const u16* Vl,
                                          char* Pw, bool diag, int lr, int lg, int w) {
  f32x4 s_acc[4];
  #pragma unroll
  for (int ct = 0; ct < 4; ++ct) s_acc[ct] = (f32x4){0.f, 0.f, 0.f, 0.f};
  __builtin_amdgcn_s_setprio(1);
  #pragma unroll
  for (int kg = 0; kg < 4; ++kg) {
    #pragma unroll
    for (int ct = 0; ct < 4; ++ct) {
      int krow = ct*16 + lr;
      int kbyte = (krow*256 + (kg*32 + lg*8)*2) ^ ((krow & 7) << 4);
      short8 bk = *(const short8*)((const char*)Kl + kbyte);
      s_acc[ct] = __builtin_amdgcn_mfma_f32_16x16x32_bf16(st.aq[kg], bk, s_acc[ct], 0, 0, 0);
    }
  }
  __builtin_amdgcn_s_setprio(0);
  float p[4][4];
  #pragma unroll
  for (int ct = 0; ct < 4; ++ct)
    #pragma unroll
    for (int r = 0; r < 4; ++r) {
      float sv = s_acc[ct][r];
      if (diag && (ct*16 + lr) > (w*16 + lg*4 + r)) sv = -INFINITY;
      p[ct][r] = sv;
    }
  float fac[4];
  #pragma unroll
  for (int r = 0; r < 4; ++r) {
    float mx = fmaxf(fmaxf(p[0][r], p[1][r]), fmaxf(p[2][r], p[3][r]));
    #pragma unroll
    for (int off = 1; off < 16; off <<= 1) mx = fmaxf(mx, __shfl_xor(mx, off));
    float mn = fmaxf(st.m_run[r], mx);
    fac[r] = __expf(st.m_run[r] - mn);
    st.m_run[r] = mn;
    float ls = 0.f;
    #pragma unroll
    for (int ct = 0; ct < 4; ++ct) { float pv = __expf(p[ct][r] - mn); p[ct][r] = pv; ls += pv; }
    #pragma unroll
    for (int off = 1; off < 16; off <<= 1) ls += __shfl_xor(ls, off);
    st.l_run[r] = st.l_run[r] * fac[r] + ls;
  }
  #pragma unroll
  for (int dt = 0; dt < 8; ++dt)
    #pragma unroll
    for (int r = 0; r < 4; ++r) st.oacc[dt][r] *= fac[r];
  #pragma unroll
  for (int ct = 0; ct < 4; ++ct)
    #pragma unroll
    for (int r = 0; r < 4; ++r) {
      int prow = lg*4 + r;
      int pb = (prow*128 + (ct*16 + lr)*2) ^ ((prow & 7) << 4);
      *(u16*)(Pw + pb) = f2bf(p[ct][r]);
    }
  asm volatile("s_waitcnt lgkmcnt(0)" ::: "memory");
  __builtin_amdgcn_sched_barrier(0);
  short8 pa[2];
  #pragma unroll
  for (int kk = 0; kk < 2; ++kk) {
    int pb = (lr*128 + (kk*32 + lg*8)*2) ^ ((lr & 7) << 4);
    pa[kk] = *(const short8*)(Pw + pb);
  }
  __builtin_amdgcn_s_setprio(1);
  #pragma unroll
  for (int dt = 0; dt < 8; ++dt) {
    #pragma unroll
    for (int kk = 0; kk < 2; ++kk) {
      int vrow = dt*16 + lr;
      int vbyte = (vrow*128 + (kk*32 + lg*8)*2) ^ ((vrow & 7) << 4);
      short8 bv = *(const short8*)((const char*)Vl + vbyte);
      st.oacc[dt] = __builtin_amdgcn_mfma_f32_16x16x32_bf16(pa[kk], bv, st.oacc[dt], 0, 0, 0);
    }
  }
  __builtin_amdgcn_s_setprio(0);
}

__device__ __forceinline__ void write_out(TileSt& st, u16* __restrict__ ao,
                                          int b, int h, int qbase, int lr, int lg, int w) {
  float invl[4];
  #pragma unroll
  for (int r = 0; r < 4; ++r) invl[r] = 1.0f / st.l_run[r];
  #pragma unroll
  for (int dt = 0; dt < 8; ++dt)
    #pragma unroll
    for (int r = 0; r < 4; ++r) {
      int t = qbase + w*16 + lg*4 + r;
      int col = h*HD_ + dt*16 + lr;
      ao[(size_t)(b * T_ + t) * C_ + col] = f2bf(st.oacc[dt][r] * invl[r]);
    }
}

__global__ __launch_bounds__(256, 2) void attn_kernel(const u16* __restrict__ qb,
    const u16* __restrict__ kb, const u16* __restrict__ vtb, u16* __restrict__ ao) {
  __shared__ u16 Kl[2][64 * 128];
  __shared__ u16 Vl[2][128 * 64];
  __shared__ u16 Pl[4][16 * 64];
  int bid0 = blockIdx.x;
  int bid = (bid0 & 7) * 128 + (bid0 >> 3);     // chunked XCD mapping (1024 % 8 == 0)
  int bh = bid >> 4, pr = bid & 15;
  int lo = pr, hi = 31 - pr;                    // paired q-tiles: lo+1 + hi+1 = 33 always
  int b = bh >> 4, h = bh & 15;
  int tid = threadIdx.x, w = tid >> 6, l = tid & 63;
  int lr = l & 15, lg = l >> 4;
  const u16* qptr = qb + (size_t)bh * T_ * HD_;
  const u16* kpl  = kb + (size_t)bh * T_ * HD_;
  const u16* vpl  = vtb + (size_t)bh * HD_ * T_;
  char* Pw = (char*)&Pl[w][0];

  TileSt stL, stH;
  #pragma unroll
  for (int kg = 0; kg < 4; ++kg) {
    stL.aq[kg] = *(const short8*)(qptr + (size_t)(lo*64 + w*16 + lr) * HD_ + kg*32 + lg*8);
    stH.aq[kg] = *(const short8*)(qptr + (size_t)(hi*64 + w*16 + lr) * HD_ + kg*32 + lg*8);
  }
  #pragma unroll
  for (int dt = 0; dt < 8; ++dt) {
    stL.oacc[dt] = (f32x4){0.f, 0.f, 0.f, 0.f};
    stH.oacc[dt] = (f32x4){0.f, 0.f, 0.f, 0.f};
  }
  #pragma unroll
  for (int r = 0; r < 4; ++r) {
    stL.m_run[r] = -INFINITY; stH.m_run[r] = -INFINITY;
    stL.l_run[r] = 0.f;       stH.l_run[r] = 0.f;
  }

  stage_kv(kpl, vpl, 0, &Kl[0][0], &Vl[0][0], w, l);
  __syncthreads();
  int cur = 0;
  for (int kt = 0; kt <= hi; ++kt) {
    if (kt < hi) stage_kv(kpl, vpl, kt + 1, &Kl[cur ^ 1][0], &Vl[cur ^ 1][0], w, l);
    attn_tile(stH, &Kl[cur][0], &Vl[cur][0], Pw, kt == hi, lr, lg, w);
    if (kt <= lo) attn_tile(stL, &Kl[cur][0], &Vl[cur][0], Pw, kt == lo, lr, lg, w);
    __syncthreads();
    cur ^= 1;
  }
  write_out(stH, ao, b, h, hi*64, lr, lg, w);
  write_out(stL, ao, b, h, lo*64, lr, lg, w);
}

extern "C" void kernel_launch(void* const* d_in, const int* in_sizes, int n_in,
                              void* d_out, int out_size, void* d_ws, size_t ws_size,
                              hipStream_t stream) {
  const float* x     = (const float*)d_in[0];
  const float* wqkv  = (const float*)d_in[1];
  const float* w_out = (const float*)d_in[2];
  float* out = (float*)d_out;

  char* ws = (char*)d_ws;
  size_t off = 0;
  u16* xb    = (u16*)(ws + off); off += (size_t)BT_ * C_ * 2;
  u16* wqkvb = (u16*)(ws + off); off += (size_t)N3_ * C_ * 2;
  u16* woutb = (u16*)(ws + off); off += (size_t)C_ * C_ * 2;
  u16* qkvb  = (u16*)(ws + off); off += (size_t)BT_ * N3_ * 2;
  u16* qbf   = (u16*)(ws + off); off += (size_t)BT_ * C_ * 2;
  u16* aob   = (u16*)(ws + off); off += (size_t)BT_ * C_ * 2;
  u16* kbb   = (u16*)(ws + off); off += (size_t)BT_ * C_ * 2;
  u16* vtb   = (u16*)(ws + off); off += (size_t)BT_ * C_ * 2;
  float* cosb = (float*)(ws + off); off += (size_t)T_ * 64 * 4;
  float* sinb = (float*)(ws + off); off += (size_t)T_ * 64 * 4;

  float* kout = out + (size_t)BT_ * C_;
  float* vout = out + 2 * (size_t)BT_ * C_;

  hipFuncSetAttribute((const void*)gemm8p_kernel<1>,
                      hipFuncAttributeMaxDynamicSharedMemorySize, 131072);
  hipFuncSetAttribute((const void*)gemm8p_kernel<0>,
                      hipFuncAttributeMaxDynamicSharedMemorySize, 131072);

  cast_f2b_kernel<<<(BT_*C_/4)/256, 256, 0, stream>>>(x, xb, BT_*C_/4);
  cast_f2b_kernel<<<(N3_*C_/4)/256, 256, 0, stream>>>(wqkv, wqkvb, N3_*C_/4);
  cast_f2b_kernel<<<(C_*C_/4)/256, 256, 0, stream>>>(w_out, woutb, C_*C_/4);
  rope_table_kernel<<<(T_*64)/256, 256, 0, stream>>>(cosb, sinb);
  gemm8p_kernel<1><<<(N3_/256)*(BT_/256), 512, 131072, stream>>>(xb, wqkvb, qkvb, BT_, N3_, C_, N3_/256);
  rope_apply_kernel<<<(B_*T_*H_*64)/256, 256, 0, stream>>>(qkvb, cosb, sinb, qbf, kbb, kout, vout);
  vt_kernel<<<B_*H_*(T_/64)*2, 256, 0, stream>>>(qkvb, vtb);
  attn_kernel<<<B_*H_*16, 256, 0, stream>>>(qbf, kbb, vtb, aob);
  gemm8p_kernel<0><<<(C_/256)*(BT_/256), 512, 131072, stream>>>(aob, woutb, out, BT_, C_, C_, C_/256);
}

// Round 6
// 571.708 us; speedup vs baseline: 1.0095x; 1.0095x over previous
//
#include <hip/hip_runtime.h>

#define B_ 4
#define T_ 2048
#define C_ 2048
#define H_ 16
#define HD_ 128
#define BT_ (B_*T_)
#define N3_ (3*C_)

typedef unsigned short u16;
typedef unsigned int u32;
using short8 = __attribute__((ext_vector_type(8))) short;
using f32x4  = __attribute__((ext_vector_type(4))) float;

__device__ __forceinline__ u16 f2bf(float f) {
  union { float f; u32 u; } v; v.f = f;
  u32 r = v.u + 0x7FFFu + ((v.u >> 16) & 1u);
  return (u16)(r >> 16);
}
__device__ __forceinline__ float bf2f(u16 u) {
  union { u32 u; float f; } v; v.u = ((u32)u) << 16;
  return v.f;
}
__device__ __forceinline__ void gload_lds16(const void* g, void* l) {
  __builtin_amdgcn_global_load_lds((const __attribute__((address_space(1))) void*)g,
                                   (__attribute__((address_space(3))) void*)l, 16, 0, 0);
}

// ---------------- cast fp32 -> bf16 ----------------
__global__ __launch_bounds__(256) void cast_f2b_kernel(const float* __restrict__ in,
                                                       u16* __restrict__ out, int n4) {
  int i = blockIdx.x * 256 + threadIdx.x;
  if (i >= n4) return;
  float4 v = ((const float4*)in)[i];
  ushort4 o;
  o.x = f2bf(v.x); o.y = f2bf(v.y); o.z = f2bf(v.z); o.w = f2bf(v.w);
  ((ushort4*)out)[i] = o;
}

// ---------------- RoPE cos/sin table [T][64] ----------------
__global__ __launch_bounds__(256) void rope_table_kernel(float* __restrict__ cosb,
                                                         float* __restrict__ sinb) {
  int i = blockIdx.x * 256 + threadIdx.x;
  int t = i >> 6, d = i & 63;
  float inv = powf(10000.0f, -(float)d / 64.0f);
  float ang = (float)t * inv;
  cosb[i] = cosf(ang);
  sinb[i] = sinf(ang);
}

// ---------------- RoPE apply + split qkv ----------------
__global__ __launch_bounds__(256) void rope_apply_kernel(const u16* __restrict__ qkv,
    const float* __restrict__ cosb, const float* __restrict__ sinb,
    u16* __restrict__ qb, u16* __restrict__ kbb,
    float* __restrict__ kout, float* __restrict__ vout) {
  int gid = blockIdx.x * 256 + threadIdx.x;   // B*T*H*64 threads
  int d = gid & 63;
  int h = (gid >> 6) & 15;
  int t = (gid >> 10) & 2047;
  int b = gid >> 21;
  const u16* row = qkv + (size_t)(b * T_ + t) * N3_;
  int base = h * HD_ + d;
  const float SCALE = 0.08838834764831845f; // 1/sqrt(128), folded into Q
  float q0 = bf2f(row[base]);
  float q1 = bf2f(row[base + 64]);
  float k0 = bf2f(row[C_ + base]);
  float k1 = bf2f(row[C_ + base + 64]);
  float v0 = bf2f(row[2*C_ + base]);
  float v1 = bf2f(row[2*C_ + base + 64]);
  float c = cosb[t * 64 + d], s = sinb[t * 64 + d];
  size_t o = ((size_t)((b * H_ + h) * T_ + t)) * HD_ + d;
  qb[o]        = f2bf((q0 * c - q1 * s) * SCALE);
  qb[o + 64]   = f2bf((q1 * c + q0 * s) * SCALE);
  float kr0 = k0 * c - k1 * s;
  float kr1 = k1 * c + k0 * s;
  kout[o]      = kr0;
  kout[o + 64] = kr1;
  kbb[o]       = f2bf(kr0);
  kbb[o + 64]  = f2bf(kr1);
  vout[o]      = v0;
  vout[o + 64] = v1;
}

// ---------------- V transpose: qkv bf16 -> Vt bf16 [B,H,hd,T] ----------------
__global__ __launch_bounds__(256) void vt_kernel(const u16* __restrict__ qkvb,
                                                 u16* __restrict__ vtb) {
  __shared__ u16 tile[64][72];
  int bid = blockIdx.x;          // bh(64) * ttile(32) * dhalf(2)
  int dh = bid & 1, tt = (bid >> 1) & 31, bh = bid >> 6;
  int b = bh >> 4, h = bh & 15;
  int tid = threadIdx.x;
  int tr = tid >> 2, tc = tid & 3;
  const u16* src = qkvb + (size_t)(b*T_ + tt*64 + tr) * N3_ + 2*C_ + h*HD_ + dh*64 + tc*16;
  short8 v0 = *(const short8*)src;
  short8 v1 = *(const short8*)(src + 8);
  #pragma unroll
  for (int j = 0; j < 8; ++j) {
    tile[tr][tc*16 + j]     = (u16)v0[j];
    tile[tr][tc*16 + 8 + j] = (u16)v1[j];
  }
  __syncthreads();
  int dr = tid >> 2, c2 = tid & 3;
  short8 o0, o1;
  #pragma unroll
  for (int j = 0; j < 8; ++j) {
    o0[j] = (short)tile[c2*16 + j][dr];
    o1[j] = (short)tile[c2*16 + 8 + j][dr];
  }
  u16* dst = vtb + ((size_t)bh * HD_ + dh*64 + dr) * T_ + tt*64 + c2*16;
  *(short8*)dst = o0;
  *(short8*)(dst + 8) = o1;
}

// ---------------- bf16 GEMM, C = A @ B^T : 256x256, 8-wave, 4-ring, per-phase lockstep ----------------
// T2: permuted-chunk LDS (0 conflicts measured R4/R5).
// T3+T4: ring-4, stage tile t+3 during t, vmcnt(8) at tile end (tiles t+2,t+3
// stay in flight; only t+1 must be resident).
// NEW (R6): m201-style per-phase discipline: {ds-reads + stage -> barrier ->
// lgkmcnt(0)+sched_barrier -> setprio(1) 16-MFMA setprio(0) -> barrier} x2 per
// K-tile. Forces wave convergence so MFMA clusters stack on the matrix pipe.
template<int OUT_BF16>
__global__ __launch_bounds__(512, 2) void gemm8p_kernel(const u16* __restrict__ A,
    const u16* __restrict__ Bw, void* __restrict__ Cout, int M, int N, int K, int ntx) {
  extern __shared__ u16 ldsx[];   // 4 slots x (A 8192 + B 8192 u16) = 128 KiB
  int lin = blockIdx.x;
  int cpx = gridDim.x >> 3;                      // grid % 8 == 0
  int wg = (lin & 7) * cpx + (lin >> 3);
  int mtile = wg / ntx, ntile = wg - mtile * ntx;
  int tid = threadIdx.x, w = tid >> 6, l = tid & 63;
  int lr = l & 15, lg = l >> 4;
  int wr = w >> 2, wc = w & 3;                   // 2x4 wave grid
  const u16* Abase = A + (size_t)mtile * 256 * K;
  const u16* Bbase = Bw + (size_t)ntile * 256 * K;

  // staging: LDS chunk s=(j*8+w)*64+l; global row=(s>>5)*8+(s&7), kchunk=(s&31)>>3
  int goff[2], ldsoff[2];
  #pragma unroll
  for (int j = 0; j < 2; ++j) {
    int s = (j*8 + w)*64 + l;
    int row = (s >> 5)*8 + (s & 7);
    int c = (s & 31) >> 3;
    goff[j] = row * K + c*8;
    ldsoff[j] = (j*8 + w) * 512;
  }
  // read-side byte offsets: byte(row,lg) = (row&~7)*64 + lg*128 + (row&7)*16
  int bbyte[4], abyte[2][4];
  #pragma unroll
  for (int n = 0; n < 4; ++n) {
    int r = wc*64 + n*16 + lr;
    bbyte[n] = ((r & ~7) << 6) + (lg << 7) + ((r & 7) << 4);
  }
  #pragma unroll
  for (int mq = 0; mq < 2; ++mq)
    #pragma unroll
    for (int m = 0; m < 4; ++m) {
      int r = wr*128 + mq*64 + m*16 + lr;
      abyte[mq][m] = ((r & ~7) << 6) + (lg << 7) + ((r & 7) << 4);
    }

  f32x4 acc[8][4];
  #pragma unroll
  for (int mi = 0; mi < 8; ++mi)
    #pragma unroll
    for (int n = 0; n < 4; ++n) acc[mi][n] = (f32x4){0.f,0.f,0.f,0.f};

  const int NT = K >> 5;
  // prologue: stage tiles 0,1,2; vmcnt(8) => tile 0 resident, 1,2 in flight
  #pragma unroll
  for (int t0 = 0; t0 < 3; ++t0) {
    const u16* ga = Abase + t0*32;
    const u16* gb = Bbase + t0*32;
    u16* la = ldsx + (size_t)t0 * 16384;
    #pragma unroll
    for (int j = 0; j < 2; ++j) gload_lds16(ga + goff[j], la + ldsoff[j]);
    #pragma unroll
    for (int j = 0; j < 2; ++j) gload_lds16(gb + goff[j], la + 8192 + ldsoff[j]);
  }
  asm volatile("s_waitcnt vmcnt(8)" ::: "memory");
  __builtin_amdgcn_s_barrier();

  for (int t = 0; t < NT; ++t) {
    const char* Al = (const char*)(ldsx + (size_t)(t & 3) * 16384);
    const char* Bl = Al + 16384;
    int tp = t + 3;
    bool stg = tp < NT;
    u16* lp = ldsx + (size_t)(tp & 3) * 16384;
    short8 bf[4], af[4];
    // ======== phase A: reads (B all 4 + A mq0) ; stage A(t+3) ; barrier ; MFMA mq0
    #pragma unroll
    for (int n = 0; n < 4; ++n) bf[n] = *(const short8*)(Bl + bbyte[n]);
    #pragma unroll
    for (int m = 0; m < 4; ++m) af[m] = *(const short8*)(Al + abyte[0][m]);
    if (stg) {
      const u16* ga = Abase + tp*32;
      #pragma unroll
      for (int j = 0; j < 2; ++j) gload_lds16(ga + goff[j], lp + ldsoff[j]);
    }
    __builtin_amdgcn_s_barrier();
    asm volatile("s_waitcnt lgkmcnt(0)" ::: "memory");
    __builtin_amdgcn_sched_barrier(0);
    __builtin_amdgcn_s_setprio(1);
    #pragma unroll
    for (int m = 0; m < 4; ++m)
      #pragma unroll
      for (int n = 0; n < 4; ++n)
        acc[m][n] = __builtin_amdgcn_mfma_f32_16x16x32_bf16(af[m], bf[n], acc[m][n], 0, 0, 0);
    __builtin_amdgcn_s_setprio(0);
    __builtin_amdgcn_s_barrier();
    // ======== phase B: reads (A mq1) ; stage B(t+3) ; counted vmcnt ; barrier ; MFMA mq1
    #pragma unroll
    for (int m = 0; m < 4; ++m) af[m] = *(const short8*)(Al + abyte[1][m]);
    if (stg) {
      const u16* gb = Bbase + tp*32;
      #pragma unroll
      for (int j = 0; j < 2; ++j) gload_lds16(gb + goff[j], lp + 8192 + ldsoff[j]);
    }
    // residency: need only tile t+1 landed before next phase A reads it.
    if (t + 3 < NT)      { asm volatile("s_waitcnt vmcnt(8)" ::: "memory"); }
    else if (t + 2 < NT) { asm volatile("s_waitcnt vmcnt(4)" ::: "memory"); }
    else                 { asm volatile("s_waitcnt vmcnt(0)" ::: "memory"); }
    __builtin_amdgcn_s_barrier();
    asm volatile("s_waitcnt lgkmcnt(0)" ::: "memory");
    __builtin_amdgcn_sched_barrier(0);
    __builtin_amdgcn_s_setprio(1);
    #pragma unroll
    for (int m = 0; m < 4; ++m)
      #pragma unroll
      for (int n = 0; n < 4; ++n)
        acc[4+m][n] = __builtin_amdgcn_mfma_f32_16x16x32_bf16(af[m], bf[n], acc[4+m][n], 0, 0, 0);
    __builtin_amdgcn_s_setprio(0);
    __builtin_amdgcn_s_barrier();
  }
  // epilogue
  #pragma unroll
  for (int mi = 0; mi < 8; ++mi)
    #pragma unroll
    for (int n = 0; n < 4; ++n)
      #pragma unroll
      for (int r = 0; r < 4; ++r) {
        int grow = mtile*256 + wr*128 + mi*16 + lg*4 + r;
        int gcol = ntile*256 + wc*64 + n*16 + lr;
        float v = acc[mi][n][r];
        if (OUT_BF16) ((u16*)Cout)[(size_t)grow * N + gcol] = f2bf(v);
        else          ((float*)Cout)[(size_t)grow * N + gcol] = v;
      }
}

// ---------------- causal flash attention, paired q-tiles, dbuf gload_lds ----------------
struct TileSt {
  short8 aq[4];
  f32x4 oacc[8];
  float m_run[4];
  float l_run[4];
};

__device__ __forceinline__ void stage_kv(const u16* kpl, const u16* vpl, int kt,
                                         u16* Kd, u16* Vd, int w, int l) {
  const u16* kTile = kpl + (size_t)kt * 64 * HD_;
  int ktOff = kt * 64;
  #pragma unroll
  for (int j = 0; j < 4; ++j) {
    int s = (j*4 + w)*64 + l;
    int g = s ^ ((s >> 4) & 7);            // K: 16 chunks/row, XOR (row&7)
    gload_lds16(kTile + (g >> 4)*HD_ + (g & 15)*8, (char*)Kd + (j*4 + w)*1024);
    int g2 = s ^ ((s >> 3) & 7);           // Vt: 8 chunks/row, XOR (d&7)
    gload_lds16(vpl + (size_t)(g2 >> 3)*T_ + ktOff + (g2 & 7)*8, (char*)Vd + (j*4 + w)*1024);
  }
}

__device__ __forceinline__ void attn_tile(TileSt& st, const u16* Kl, const u16* Vl,
                                          char* Pw, bool diag, int lr, int lg, int w) {
  f32x4 s_acc[4];
  #pragma unroll
  for (int ct = 0; ct < 4; ++ct) s_acc[ct] = (f32x4){0.f, 0.f, 0.f, 0.f};
  __builtin_amdgcn_s_setprio(1);
  #pragma unroll
  for (int kg = 0; kg < 4; ++kg) {
    #pragma unroll
    for (int ct = 0; ct < 4; ++ct) {
      int krow = ct*16 + lr;
      int kbyte = (krow*256 + (kg*32 + lg*8)*2) ^ ((krow & 7) << 4);
      short8 bk = *(const short8*)((const char*)Kl + kbyte);
      s_acc[ct] = __builtin_amdgcn_mfma_f32_16x16x32_bf16(st.aq[kg], bk, s_acc[ct], 0, 0, 0);
    }
  }
  __builtin_amdgcn_s_setprio(0);
  float p[4][4];
  #pragma unroll
  for (int ct = 0; ct < 4; ++ct)
    #pragma unroll
    for (int r = 0; r < 4; ++r) {
      float sv = s_acc[ct][r];
      if (diag && (ct*16 + lr) > (w*16 + lg*4 + r)) sv = -INFINITY;
      p[ct][r] = sv;
    }
  float fac[4];
  #pragma unroll
  for (int r = 0; r < 4; ++r) {
    float mx = fmaxf(fmaxf(p[0][r], p[1][r]), fmaxf(p[2][r], p[3][r]));
    #pragma unroll
    for (int off = 1; off < 16; off <<= 1) mx = fmaxf(mx, __shfl_xor(mx, off));
    float mn = fmaxf(st.m_run[r], mx);
    fac[r] = __expf(st.m_run[r] - mn);
    st.m_run[r] = mn;
    float ls = 0.f;
    #pragma unroll
    for (int ct = 0; ct < 4; ++ct) { float pv = __expf(p[ct][r] - mn); p[ct][r] = pv; ls += pv; }
    #pragma unroll
    for (int off = 1; off < 16; off <<= 1) ls += __shfl_xor(ls, off);
    st.l_run[r] = st.l_run[r] * fac[r] + ls;
  }
  #pragma unroll
  for (int dt = 0; dt < 8; ++dt)
    #pragma unroll
    for (int r = 0; r < 4; ++r) st.oacc[dt][r] *= fac[r];
  #pragma unroll
  for (int ct = 0; ct < 4; ++ct)
    #pragma unroll
    for (int r = 0; r < 4; ++r) {
      int prow = lg*4 + r;
      int pb = (prow*128 + (ct*16 + lr)*2) ^ ((prow & 7) << 4);
      *(u16*)(Pw + pb) = f2bf(p[ct][r]);
    }
  asm volatile("s_waitcnt lgkmcnt(0)" ::: "memory");
  __builtin_amdgcn_sched_barrier(0);
  short8 pa[2];
  #pragma unroll
  for (int kk = 0; kk < 2; ++kk) {
    int pb = (lr*128 + (kk*32 + lg*8)*2) ^ ((lr & 7) << 4);
    pa[kk] = *(const short8*)(Pw + pb);
  }
  __builtin_amdgcn_s_setprio(1);
  #pragma unroll
  for (int dt = 0; dt < 8; ++dt) {
    #pragma unroll
    for (int kk = 0; kk < 2; ++kk) {
      int vrow = dt*16 + lr;
      int vbyte = (vrow*128 + (kk*32 + lg*8)*2) ^ ((vrow & 7) << 4);
      short8 bv = *(const short8*)((const char*)Vl + vbyte);
      st.oacc[dt] = __builtin_amdgcn_mfma_f32_16x16x32_bf16(pa[kk], bv, st.oacc[dt], 0, 0, 0);
    }
  }
  __builtin_amdgcn_s_setprio(0);
}

__device__ __forceinline__ void write_out(TileSt& st, u16* __restrict__ ao,
                                          int b, int h, int qbase, int lr, int lg, int w) {
  float invl[4];
  #pragma unroll
  for (int r = 0; r < 4; ++r) invl[r] = 1.0f / st.l_run[r];
  #pragma unroll
  for (int dt = 0; dt < 8; ++dt)
    #pragma unroll
    for (int r = 0; r < 4; ++r) {
      int t = qbase + w*16 + lg*4 + r;
      int col = h*HD_ + dt*16 + lr;
      ao[(size_t)(b * T_ + t) * C_ + col] = f2bf(st.oacc[dt][r] * invl[r]);
    }
}

__global__ __launch_bounds__(256, 2) void attn_kernel(const u16* __restrict__ qb,
    const u16* __restrict__ kb, const u16* __restrict__ vtb, u16* __restrict__ ao) {
  __shared__ u16 Kl[2][64 * 128];
  __shared__ u16 Vl[2][128 * 64];
  __shared__ u16 Pl[4][16 * 64];
  int bid0 = blockIdx.x;
  int bid = (bid0 & 7) * 128 + (bid0 >> 3);     // chunked XCD mapping (1024 % 8 == 0)
  int bh = bid >> 4, pr = bid & 15;
  int lo = pr, hi = 31 - pr;                    // paired q-tiles: lo+1 + hi+1 = 33 always
  int b = bh >> 4, h = bh & 15;
  int tid = threadIdx.x, w = tid >> 6, l = tid & 63;
  int lr = l & 15, lg = l >> 4;
  const u16* qptr = qb + (size_t)bh * T_ * HD_;
  const u16* kpl  = kb + (size_t)bh * T_ * HD_;
  const u16* vpl  = vtb + (size_t)bh * HD_ * T_;
  char* Pw = (char*)&Pl[w][0];

  TileSt stL, stH;
  #pragma unroll
  for (int kg = 0; kg < 4; ++kg) {
    stL.aq[kg] = *(const short8*)(qptr + (size_t)(lo*64 + w*16 + lr) * HD_ + kg*32 + lg*8);
    stH.aq[kg] = *(const short8*)(qptr + (size_t)(hi*64 + w*16 + lr) * HD_ + kg*32 + lg*8);
  }
  #pragma unroll
  for (int dt = 0; dt < 8; ++dt) {
    stL.oacc[dt] = (f32x4){0.f, 0.f, 0.f, 0.f};
    stH.oacc[dt] = (f32x4){0.f, 0.f, 0.f, 0.f};
  }
  #pragma unroll
  for (int r = 0; r < 4; ++r) {
    stL.m_run[r] = -INFINITY; stH.m_run[r] = -INFINITY;
    stL.l_run[r] = 0.f;       stH.l_run[r] = 0.f;
  }

  stage_kv(kpl, vpl, 0, &Kl[0][0], &Vl[0][0], w, l);
  __syncthreads();
  int cur = 0;
  for (int kt = 0; kt <= hi; ++kt) {
    if (kt < hi) stage_kv(kpl, vpl, kt + 1, &Kl[cur ^ 1][0], &Vl[cur ^ 1][0], w, l);
    attn_tile(stH, &Kl[cur][0], &Vl[cur][0], Pw, kt == hi, lr, lg, w);
    if (kt <= lo) attn_tile(stL, &Kl[cur][0], &Vl[cur][0], Pw, kt == lo, lr, lg, w);
    __syncthreads();
    cur ^= 1;
  }
  write_out(stH, ao, b, h, hi*64, lr, lg, w);
  write_out(stL, ao, b, h, lo*64, lr, lg, w);
}

extern "C" void kernel_launch(void* const* d_in, const int* in_sizes, int n_in,
                              void* d_out, int out_size, void* d_ws, size_t ws_size,
                              hipStream_t stream) {
  const float* x     = (const float*)d_in[0];
  const float* wqkv  = (const float*)d_in[1];
  const float* w_out = (const float*)d_in[2];
  float* out = (float*)d_out;

  char* ws = (char*)d_ws;
  size_t off = 0;
  u16* xb    = (u16*)(ws + off); off += (size_t)BT_ * C_ * 2;
  u16* wqkvb = (u16*)(ws + off); off += (size_t)N3_ * C_ * 2;
  u16* woutb = (u16*)(ws + off); off += (size_t)C_ * C_ * 2;
  u16* qkvb  = (u16*)(ws + off); off += (size_t)BT_ * N3_ * 2;
  u16* qbf   = (u16*)(ws + off); off += (size_t)BT_ * C_ * 2;
  u16* aob   = (u16*)(ws + off); off += (size_t)BT_ * C_ * 2;
  u16* kbb   = (u16*)(ws + off); off += (size_t)BT_ * C_ * 2;
  u16* vtb   = (u16*)(ws + off); off += (size_t)BT_ * C_ * 2;
  float* cosb = (float*)(ws + off); off += (size_t)T_ * 64 * 4;
  float* sinb = (float*)(ws + off); off += (size_t)T_ * 64 * 4;

  float* kout = out + (size_t)BT_ * C_;
  float* vout = out + 2 * (size_t)BT_ * C_;

  hipFuncSetAttribute((const void*)gemm8p_kernel<1>,
                      hipFuncAttributeMaxDynamicSharedMemorySize, 131072);
  hipFuncSetAttribute((const void*)gemm8p_kernel<0>,
                      hipFuncAttributeMaxDynamicSharedMemorySize, 131072);

  cast_f2b_kernel<<<(BT_*C_/4)/256, 256, 0, stream>>>(x, xb, BT_*C_/4);
  cast_f2b_kernel<<<(N3_*C_/4)/256, 256, 0, stream>>>(wqkv, wqkvb, N3_*C_/4);
  cast_f2b_kernel<<<(C_*C_/4)/256, 256, 0, stream>>>(w_out, woutb, C_*C_/4);
  rope_table_kernel<<<(T_*64)/256, 256, 0, stream>>>(cosb, sinb);
  gemm8p_kernel<1><<<(N3_/256)*(BT_/256), 512, 131072, stream>>>(xb, wqkvb, qkvb, BT_, N3_, C_, N3_/256);
  rope_apply_kernel<<<(B_*T_*H_*64)/256, 256, 0, stream>>>(qkvb, cosb, sinb, qbf, kbb, kout, vout);
  vt_kernel<<<B_*H_*(T_/64)*2, 256, 0, stream>>>(qkvb, vtb);
  attn_kernel<<<B_*H_*16, 256, 0, stream>>>(qbf, kbb, vtb, aob);
  gemm8p_kernel<0><<<(C_/256)*(BT_/256), 512, 131072, stream>>>(aob, woutb, out, BT_, C_, C_, C_/256);
}